// Round 5
// baseline (330.562 us; speedup 1.0000x reference)
//
#include <hip/hip_runtime.h>

#define TT   256
#define HID  30
#define LOG2E 1.4426950408889634f
#define HS   40   // h-row stride in bf16: 80B, rows stay 16B-aligned for b128
#define NS   4    // h0 ring slots

typedef __bf16 bf16x8_t __attribute__((ext_vector_type(8)));
typedef float  f32x4_t  __attribute__((ext_vector_type(4)));

__device__ __forceinline__ float fexp2(float x){
#if __has_builtin(__builtin_amdgcn_exp2f)
    return __builtin_amdgcn_exp2f(x);
#else
    return exp2f(x);
#endif
}
__device__ __forceinline__ float frcp(float x){
#if __has_builtin(__builtin_amdgcn_rcpf)
    return __builtin_amdgcn_rcpf(x);
#else
    return 1.f/x;
#endif
}
__device__ __forceinline__ float fsigmoid(float x){ return frcp(1.f + fexp2(-LOG2E*x)); }
__device__ __forceinline__ f32x4_t exp4(f32x4_t v){
    f32x4_t e; e[0]=fexp2(v[0]); e[1]=fexp2(v[1]); e[2]=fexp2(v[2]); e[3]=fexp2(v[3]); return e;
}
__device__ __forceinline__ f32x4_t rcp4(f32x4_t v){
    f32x4_t r; r[0]=frcp(v[0]); r[1]=frcp(v[1]); r[2]=frcp(v[2]); r[3]=frcp(v[3]); return r;
}
__device__ __forceinline__ f32x4_t splat4(float v){ f32x4_t r = {v,v,v,v}; return r; }

__device__ __forceinline__ int ld_acq(int* p){
    return __hip_atomic_load(p, __ATOMIC_ACQUIRE, __HIP_MEMORY_SCOPE_WORKGROUP);
}
__device__ __forceinline__ void st_rel(int* p, int v){
    __hip_atomic_store(p, v, __ATOMIC_RELEASE, __HIP_MEMORY_SCOPE_WORKGROUP);
}

// Accs arrive pre-scaled into exp2 domain (scale folded into bf16 weights):
//   aI,aF,aO = -LOG2E*z ; aG = +2*LOG2E*z
// Merged-rcp activation: 28 trans insts (20 exp + 8 rcp) per 4-vec.
__device__ __forceinline__ f32x4_t lstm_act(f32x4_t aI, f32x4_t aF, f32x4_t aG,
                                            f32x4_t aO, f32x4_t& cst){
    f32x4_t eI = exp4(aI);
    f32x4_t eF = exp4(aF);
    f32x4_t eG = exp4(aG);
    f32x4_t eO = exp4(aO);
    f32x4_t D1 = eF + 1.f;
    f32x4_t tG = eG + 1.f;
    f32x4_t D2 = eI*tG + tG;           // (1+eI)(1+eG)
    f32x4_t r  = rcp4(D1*D2);
    f32x4_t f  = r*D2;                 // sigmoid(zf)
    f32x4_t p  = (eG - 1.f) * (r*D1);  // i*tanh(zg)
    cst = f*cst + p;
    f32x4_t cc;                        // clamp so e^{2c} can't overflow
    cc[0]=fminf(fmaxf(cst[0],-30.f),30.f);
    cc[1]=fminf(fmaxf(cst[1],-30.f),30.f);
    cc[2]=fminf(fmaxf(cst[2],-30.f),30.f);
    cc[3]=fminf(fmaxf(cst[3],-30.f),30.f);
    f32x4_t eC = exp4(cc * (2.f*LOG2E));
    f32x4_t tC = eC + 1.f;
    f32x4_t dn = eO*tC + tC;           // (1+eO)(1+eC)
    return (eC - 1.f) * rcp4(dn);
}

// R5: barrier-free decoupled pipeline.
// 256-thread block, grid 256 (1 block/CU), 32 rows/block.
// 4 fully independent waves: wv0=L0(rows 0-15), wv1=L0(rows 16-31),
// wv2=L1(rows 0-15), wv3=L1(rows 16-29). Each wave owns ALL 30 hidden
// units of its layer (2 MFMA column-halves), so the recurrence round-trip
// (h write -> A-frag read next step) is same-wave-only: NO barrier.
// L0 -> L1 handoff per team via a 4-slot LDS ring + seq/cons flags
// (acquire/release, workgroup scope). No __syncthreads between the staging
// prologue and the FC head.
__global__ __launch_bounds__(256, 1)
void lstm_fused(const float* __restrict__ x,
    const float* __restrict__ Wih0, const float* __restrict__ Whh0,
    const float* __restrict__ bih0, const float* __restrict__ bhh0,
    const float* __restrict__ Wih1, const float* __restrict__ Whh1,
    const float* __restrict__ bih1, const float* __restrict__ bhh1,
    const float* __restrict__ Wfc1, const float* __restrict__ bfc1,
    const float* __restrict__ Wfc2, const float* __restrict__ bfc2,
    const float* __restrict__ Wfc3, const float* __restrict__ bfc3,
    float* __restrict__ out)
{
    __shared__ __align__(16) float  xlds2[TT][32];      // x feature 2, f32 (32KB)
    __shared__ __align__(16) __bf16 xlds01[TT][32][2];  // x features 0,1 bf16 (32KB)
    __shared__ __align__(16) __bf16 h0s[2][NS][16][HS]; // h0 ring per team (10KB)
    __shared__ __align__(16) __bf16 h1s[2][16][HS];     // h1 single buffer (2.5KB)
    __shared__ float h1_last[32][32];
    __shared__ float zbuf[32][64];
    __shared__ float z2buf[32][32];
    __shared__ int   flags[2][2];   // [team][0]=seq(L0 steps done) [1]=cons(L1 reads done)

    const int tid  = threadIdx.x;
    const int lane = tid & 63;
    const int wv   = tid >> 6;      // 0..3
    const int role = wv >> 1;       // 0: layer0, 1: layer1
    const int team = wv & 1;        // row sub-team (16 rows each)
    const int n    = lane & 15;
    const int q    = lane >> 4;
    const int q4   = q*4;
    const int t16  = team*16;
    const int bbase = blockIdx.x * 32;

    // ---- resident per-gate, per-column-half B-fragments (scale folded) ----
    bf16x8_t fA[4][2], fB[4][2];
    float bvv[4][2], wxv[4][2];
    {
        const float scl[4] = {-LOG2E, -LOG2E, 2.f*LOG2E, -LOG2E}; // i,f,g,o
        #pragma unroll
        for (int g = 0; g < 4; ++g) {
            #pragma unroll
            for (int ch = 0; ch < 2; ++ch) {
                const int u = ch*16 + n;
                const bool ok = (u < HID);
                const int uq = ok ? u : 0;
                const int row = g*HID + uq;
                const float sg = scl[g];
                bf16x8_t va{}, vb{};
                #pragma unroll
                for (int j = 0; j < 8; ++j) {
                    int k = q*8 + j;
                    float a = 0.f, b = 0.f;
                    if (ok) {
                        if (role == 0) {
                            if (k < HID)       a = Whh0[row*HID + k];
                            else if (k == 30)  a = Wih0[row*3 + 0];
                            else if (k == 31)  a = Wih0[row*3 + 1];
                        } else {
                            if (k < HID) { a = Wih1[row*HID + k];  b = Whh1[row*HID + k]; }
                        }
                    }
                    va[j] = (__bf16)(sg*a);
                    vb[j] = (__bf16)(sg*b);
                }
                fA[g][ch] = va;  fB[g][ch] = vb;
                float bb = 0.f, ww = 0.f;
                if (ok) {
                    bb = role ? (bih1[row] + bhh1[row]) : (bih0[row] + bhh0[row]);
                    if (role == 0) ww = Wih0[row*3 + 2];
                }
                bvv[g][ch] = sg*bb;
                wxv[g][ch] = sg*ww;
            }
        }
    }

    // ---- zero h tiles, stage x into LDS, init flags ----
    for (int i = tid; i < 2*NS*16*HS/2; i += 256)   // h0s as u32
        ((uint32_t*)&h0s[0][0][0][0])[i] = 0u;
    for (int i = tid; i < 2*16*HS/2; i += 256)      // h1s as u32
        ((uint32_t*)&h1s[0][0][0])[i] = 0u;
    {
        const float* xg = x + (size_t)bbase*(TT*3);
        for (int i4 = tid*4; i4 < 32*TT*3; i4 += 256*4) {
            int row = i4 / (TT*3), tc0 = i4 % (TT*3);
            f32x4_t v = *(const f32x4_t*)(xg + (size_t)row*(TT*3) + tc0);
            #pragma unroll
            for (int j = 0; j < 4; ++j) {
                int tc = tc0 + j;
                int t = tc/3, c = tc - 3*t;
                if (c == 2) xlds2[t][row] = v[j];
                else        xlds01[t][row][c] = (__bf16)v[j];
            }
        }
    }
    if (tid == 0) { flags[0][0]=0; flags[0][1]=0; flags[1][0]=0; flags[1][1]=0; }
    __syncthreads();

    if (role == 0) {
        // =========================== LAYER-0 wave ===========================
        f32x4_t cstA = {0,0,0,0}, cstB = {0,0,0,0};
        int consv = 0;
        // prologue: x(0) into read-slot NS-1 cols 30,31
        if (lane < 16)
            *(uint32_t*)&h0s[team][NS-1][lane][30] = *(const uint32_t*)&xlds01[0][t16+lane][0];
        f32x4_t  x2   = *(const f32x4_t*)&xlds2[0][t16 + q4];
        uint32_t x01v = *(const uint32_t*)&xlds01[1][t16 + (lane & 15)][0];

#define STEP_L0(T, RS, WS) do {                                                \
    bf16x8_t A0 = *(const bf16x8_t*)&h0s[team][RS][n][q*8];                    \
    f32x4_t aI0 = __builtin_amdgcn_mfma_f32_16x16x32_bf16(A0, fA[0][0], splat4(bvv[0][0]) + x2*wxv[0][0], 0,0,0); \
    f32x4_t aF0 = __builtin_amdgcn_mfma_f32_16x16x32_bf16(A0, fA[1][0], splat4(bvv[1][0]) + x2*wxv[1][0], 0,0,0); \
    f32x4_t aG0 = __builtin_amdgcn_mfma_f32_16x16x32_bf16(A0, fA[2][0], splat4(bvv[2][0]) + x2*wxv[2][0], 0,0,0); \
    f32x4_t aO0 = __builtin_amdgcn_mfma_f32_16x16x32_bf16(A0, fA[3][0], splat4(bvv[3][0]) + x2*wxv[3][0], 0,0,0); \
    f32x4_t aI1 = __builtin_amdgcn_mfma_f32_16x16x32_bf16(A0, fA[0][1], splat4(bvv[0][1]) + x2*wxv[0][1], 0,0,0); \
    f32x4_t aF1 = __builtin_amdgcn_mfma_f32_16x16x32_bf16(A0, fA[1][1], splat4(bvv[1][1]) + x2*wxv[1][1], 0,0,0); \
    f32x4_t aG1 = __builtin_amdgcn_mfma_f32_16x16x32_bf16(A0, fA[2][1], splat4(bvv[2][1]) + x2*wxv[2][1], 0,0,0); \
    f32x4_t aO1 = __builtin_amdgcn_mfma_f32_16x16x32_bf16(A0, fA[3][1], splat4(bvv[3][1]) + x2*wxv[3][1], 0,0,0); \
    f32x4_t hA = lstm_act(aI0, aF0, aG0, aO0, cstA);                           \
    f32x4_t hB = lstm_act(aI1, aF1, aG1, aO1, cstB);                           \
    h0s[team][WS][q4  ][n] = (__bf16)hA[0];                                    \
    h0s[team][WS][q4+1][n] = (__bf16)hA[1];                                    \
    h0s[team][WS][q4+2][n] = (__bf16)hA[2];                                    \
    h0s[team][WS][q4+3][n] = (__bf16)hA[3];                                    \
    if (n < 14) {                                                              \
        h0s[team][WS][q4  ][16+n] = (__bf16)hB[0];                             \
        h0s[team][WS][q4+1][16+n] = (__bf16)hB[1];                             \
        h0s[team][WS][q4+2][16+n] = (__bf16)hB[2];                             \
        h0s[team][WS][q4+3][16+n] = (__bf16)hB[3];                             \
    }                                                                          \
    if (lane < 16) *(uint32_t*)&h0s[team][WS][lane][30] = x01v;                \
    if (lane == 0) st_rel(&flags[team][0], (T)+1);                             \
    if ((T)+1 >= NS) {                                                         \
        while (consv < (T)-(NS-2)) consv = ld_acq(&flags[team][1]);            \
    }                                                                          \
    { int tn = ((T)+2 < TT) ? (T)+2 : TT-1;                                    \
      x01v = *(const uint32_t*)&xlds01[tn][t16 + (lane & 15)][0]; }            \
    { int tx = ((T)+1 < TT) ? (T)+1 : TT-1;                                    \
      x2 = *(const f32x4_t*)&xlds2[tx][t16 + q4]; }                            \
} while (0)

        #pragma unroll 1
        for (int it = 0; it < TT/4; ++it) {
            const int T0 = it*4;
            STEP_L0(T0+0, 3, 0);
            STEP_L0(T0+1, 0, 1);
            STEP_L0(T0+2, 1, 2);
            STEP_L0(T0+3, 2, 3);
        }
#undef STEP_L0
    } else {
        // =========================== LAYER-1 wave ===========================
        f32x4_t cstA = {0,0,0,0}, cstB = {0,0,0,0};
        int seqv = 0;

#define STEP_L1(T, SLOT, LAST) do {                                            \
    while (seqv < (T)+1) seqv = ld_acq(&flags[team][0]);                       \
    bf16x8_t A1 = *(const bf16x8_t*)&h0s[team][SLOT][n][q*8];                  \
    bf16x8_t A2 = *(const bf16x8_t*)&h1s[team][n][q*8];                        \
    if (lane == 0) st_rel(&flags[team][1], (T)+1);                             \
    f32x4_t aI0 = __builtin_amdgcn_mfma_f32_16x16x32_bf16(A2, fB[0][0], splat4(bvv[0][0]), 0,0,0); \
    f32x4_t aF0 = __builtin_amdgcn_mfma_f32_16x16x32_bf16(A2, fB[1][0], splat4(bvv[1][0]), 0,0,0); \
    f32x4_t aG0 = __builtin_amdgcn_mfma_f32_16x16x32_bf16(A2, fB[2][0], splat4(bvv[2][0]), 0,0,0); \
    f32x4_t aO0 = __builtin_amdgcn_mfma_f32_16x16x32_bf16(A2, fB[3][0], splat4(bvv[3][0]), 0,0,0); \
    f32x4_t aI1 = __builtin_amdgcn_mfma_f32_16x16x32_bf16(A2, fB[0][1], splat4(bvv[0][1]), 0,0,0); \
    f32x4_t aF1 = __builtin_amdgcn_mfma_f32_16x16x32_bf16(A2, fB[1][1], splat4(bvv[1][1]), 0,0,0); \
    f32x4_t aG1 = __builtin_amdgcn_mfma_f32_16x16x32_bf16(A2, fB[2][1], splat4(bvv[2][1]), 0,0,0); \
    f32x4_t aO1 = __builtin_amdgcn_mfma_f32_16x16x32_bf16(A2, fB[3][1], splat4(bvv[3][1]), 0,0,0); \
    aI0 = __builtin_amdgcn_mfma_f32_16x16x32_bf16(A1, fA[0][0], aI0, 0,0,0);   \
    aF0 = __builtin_amdgcn_mfma_f32_16x16x32_bf16(A1, fA[1][0], aF0, 0,0,0);   \
    aG0 = __builtin_amdgcn_mfma_f32_16x16x32_bf16(A1, fA[2][0], aG0, 0,0,0);   \
    aO0 = __builtin_amdgcn_mfma_f32_16x16x32_bf16(A1, fA[3][0], aO0, 0,0,0);   \
    aI1 = __builtin_amdgcn_mfma_f32_16x16x32_bf16(A1, fA[0][1], aI1, 0,0,0);   \
    aF1 = __builtin_amdgcn_mfma_f32_16x16x32_bf16(A1, fA[1][1], aF1, 0,0,0);   \
    aG1 = __builtin_amdgcn_mfma_f32_16x16x32_bf16(A1, fA[2][1], aG1, 0,0,0);   \
    aO1 = __builtin_amdgcn_mfma_f32_16x16x32_bf16(A1, fA[3][1], aO1, 0,0,0);   \
    f32x4_t hA = lstm_act(aI0, aF0, aG0, aO0, cstA);                           \
    f32x4_t hB = lstm_act(aI1, aF1, aG1, aO1, cstB);                           \
    h1s[team][q4  ][n] = (__bf16)hA[0];                                        \
    h1s[team][q4+1][n] = (__bf16)hA[1];                                        \
    h1s[team][q4+2][n] = (__bf16)hA[2];                                        \
    h1s[team][q4+3][n] = (__bf16)hA[3];                                        \
    if (n < 14) {                                                              \
        h1s[team][q4  ][16+n] = (__bf16)hB[0];                                 \
        h1s[team][q4+1][16+n] = (__bf16)hB[1];                                 \
        h1s[team][q4+2][16+n] = (__bf16)hB[2];                                 \
        h1s[team][q4+3][16+n] = (__bf16)hB[3];                                 \
    }                                                                          \
    if (LAST) {                                                                \
        h1_last[t16+q4  ][n] = hA[0];                                          \
        h1_last[t16+q4+1][n] = hA[1];                                          \
        h1_last[t16+q4+2][n] = hA[2];                                          \
        h1_last[t16+q4+3][n] = hA[3];                                          \
        if (n < 14) {                                                          \
            h1_last[t16+q4  ][16+n] = hB[0];                                   \
            h1_last[t16+q4+1][16+n] = hB[1];                                   \
            h1_last[t16+q4+2][16+n] = hB[2];                                   \
            h1_last[t16+q4+3][16+n] = hB[3];                                   \
        }                                                                      \
    }                                                                          \
    seqv = ld_acq(&flags[team][0]);                                            \
} while (0)

        #pragma unroll 1
        for (int it = 0; it < TT/4; ++it) {
            const int T0 = it*4;
            STEP_L1(T0+0, 0, 0);
            STEP_L1(T0+1, 1, 0);
            STEP_L1(T0+2, 2, 0);
            STEP_L1(T0+3, 3, (it == TT/4 - 1));
        }
#undef STEP_L1
    }

    __syncthreads();

    // ---- FC head (256 threads, 32 rows) ----
    #pragma unroll
    for (int rep = 0; rep < 8; ++rep) {
        int idx = tid + rep*256;          // 32*64 outputs
        int m = idx >> 6, uu = idx & 63;
        float a = bfc1[uu];
        for (int k = 0; k < HID; ++k) a += h1_last[m][k] * Wfc1[uu*HID+k];
        zbuf[m][uu] = fmaxf(a, 0.f);
    }
    __syncthreads();
    #pragma unroll
    for (int rep = 0; rep < 4; ++rep) {
        int idx = tid + rep*256;          // 32*32 outputs
        int m = idx >> 5, v = idx & 31;
        float a = bfc2[v];
        for (int k = 0; k < 64; ++k) a += zbuf[m][k] * Wfc2[v*64+k];
        z2buf[m][v] = fmaxf(a, 0.f);
    }
    __syncthreads();
    if (tid < 32) {
        float a = bfc3[0];
        for (int k = 0; k < 32; ++k) a += z2buf[tid][k] * Wfc3[k];
        out[bbase + tid] = fsigmoid(a);
    }
}

extern "C" void kernel_launch(void* const* d_in, const int* in_sizes, int n_in,
                              void* d_out, int out_size, void* d_ws, size_t ws_size,
                              hipStream_t stream) {
    const float* x    = (const float*)d_in[0];
    const float* Wih0 = (const float*)d_in[1];
    const float* Whh0 = (const float*)d_in[2];
    const float* bih0 = (const float*)d_in[3];
    const float* bhh0 = (const float*)d_in[4];
    const float* Wih1 = (const float*)d_in[5];
    const float* Whh1 = (const float*)d_in[6];
    const float* bih1 = (const float*)d_in[7];
    const float* bhh1 = (const float*)d_in[8];
    const float* Wfc1 = (const float*)d_in[9];
    const float* bfc1 = (const float*)d_in[10];
    const float* Wfc2 = (const float*)d_in[11];
    const float* bfc2 = (const float*)d_in[12];
    const float* Wfc3 = (const float*)d_in[13];
    const float* bfc3 = (const float*)d_in[14];
    float* outp = (float*)d_out;

    hipLaunchKernelGGL(lstm_fused, dim3(256), dim3(256), 0, stream,
        x, Wih0, Whh0, bih0, bhh0, Wih1, Whh1, bih1, bhh1,
        Wfc1, bfc1, Wfc2, bfc2, Wfc3, bfc3, outp);
}